// Round 4
// baseline (263.661 us; speedup 1.0000x reference)
//
#include <hip/hip_runtime.h>
#include <hip/hip_bf16.h>
#include <math.h>

#define B_ 2
#define L_ 2048
#define D_ 1024
#define H_ 16
#define DH 64
#define ML (B_*L_)      // 4096
#define QKV_N 3072

typedef __attribute__((ext_vector_type(8)))  short bf16x8;
typedef __attribute__((ext_vector_type(4)))  float f32x4;
typedef __attribute__((ext_vector_type(16))) float f32x16;
typedef unsigned short u16;

__device__ __forceinline__ u16 f2bf(float f) {
    union { float f; unsigned u; } v; v.f = f;
    unsigned r = (v.u + 0x7FFFu + ((v.u >> 16) & 1u)) >> 16;
    return (u16)r;
}

__device__ __forceinline__ float fexp2(float x) {
    float r; asm("v_exp_f32 %0, %1" : "=v"(r) : "v"(x)); return r;
}

// async global->LDS, 16B per lane (lds dest must be linear base + lane*16).
__device__ __forceinline__ void async16(void* lds, const void* g) {
    __builtin_amdgcn_global_load_lds(
        (__attribute__((address_space(1))) unsigned int*)g,
        (__attribute__((address_space(3))) unsigned int*)lds,
        16, 0, 0);
}

// ---------------------------------------------------------------------------
// pack Wq,Wk,Wv,Wo (each 1M elements) into Wcat bf16 [4096][1024]
// ---------------------------------------------------------------------------
__global__ __launch_bounds__(256)
void cast_w4(const float* __restrict__ Wq, const float* __restrict__ Wk,
             const float* __restrict__ Wv, const float* __restrict__ Wo,
             u16* __restrict__ dst) {
    int i = (blockIdx.x * 256 + threadIdx.x) * 4;     // 0..4M-1
    int sel = i >> 20;
    const float* s = sel == 0 ? Wq : sel == 1 ? Wk : sel == 2 ? Wv : Wo;
    float4 v = *(const float4*)(s + (i & 1048575));
    ushort4 o;
    o.x = f2bf(v.x); o.y = f2bf(v.y); o.z = f2bf(v.z); o.w = f2bf(v.w);
    *(ushort4*)(dst + i) = o;
}

// ---------------------------------------------------------------------------
// Gates + x->bf16 cast fused. Block = 16 rows x 32 gates. Log2-domain out:
// LWG  = log2(sigmoid(x.Ww + bw)); GLOG = log2((1-sigmoid(x.We+be))*0.95+1e-8)
// ---------------------------------------------------------------------------
__global__ __launch_bounds__(256)
void gates_castx(const float* __restrict__ x,
                 const float* __restrict__ Ww, const float* __restrict__ bw,
                 const float* __restrict__ We, const float* __restrict__ be,
                 u16* __restrict__ xb,
                 float* __restrict__ GLOG, float* __restrict__ LWG) {
    __shared__ float xs[16][132];
    __shared__ float ws[32][132];
    int r0 = blockIdx.x * 16;
    int t = threadIdx.x;
    int r = t >> 4, h = t & 15;
    float sw = 0.f, se = 0.f;
    for (int k0 = 0; k0 < D_; k0 += 128) {
#pragma unroll
        for (int i = 0; i < 2; i++) {
            int c = (i * 256 + t) * 4;
            int rr = c >> 7, kk = c & 127;
            float4 xv = *(const float4*)&x[(size_t)(r0 + rr) * D_ + k0 + kk];
            *(float4*)&xs[rr][kk] = xv;
            ushort4 o;
            o.x = f2bf(xv.x); o.y = f2bf(xv.y); o.z = f2bf(xv.z); o.w = f2bf(xv.w);
            *(ushort4*)&xb[(size_t)(r0 + rr) * D_ + k0 + kk] = o;
        }
#pragma unroll
        for (int i = 0; i < 4; i++) {
            int c = (i * 256 + t) * 4;
            int rr = c >> 7, kk = c & 127;
            const float* src = rr < 16 ? &Ww[(size_t)rr * D_ + k0 + kk]
                                       : &We[(size_t)(rr - 16) * D_ + k0 + kk];
            *(float4*)&ws[rr][kk] = *(const float4*)src;
        }
        __syncthreads();
#pragma unroll
        for (int kk = 0; kk < 128; kk += 4) {
            float4 xv = *(const float4*)&xs[r][kk];
            float4 w1 = *(const float4*)&ws[h][kk];
            float4 w2 = *(const float4*)&ws[16 + h][kk];
            sw += xv.x * w1.x + xv.y * w1.y + xv.z * w1.z + xv.w * w1.w;
            se += xv.x * w2.x + xv.y * w2.y + xv.z * w2.z + xv.w * w2.w;
        }
        __syncthreads();
    }
    int row = r0 + r; int b = row >> 11, l = row & 2047;
    float wgv = 1.f / (1.f + __expf(-(sw + bw[h])));
    float egv = 1.f / (1.f + __expf(-(se + be[h])));
    size_t idx = ((size_t)(b * H_ + h)) * L_ + l;
    LWG[idx]  = __log2f(wgv);
    GLOG[idx] = __log2f((1.f - egv) * 0.95f + 1e-8f);
}

// ---------------------------------------------------------------------------
// Inclusive scan per (b,h): CC = cumsum(GLOG); CJW = CC - LWG   (log2 domain)
// ---------------------------------------------------------------------------
__global__ __launch_bounds__(64)
void scan_kernel(const float* __restrict__ GLOG, const float* __restrict__ LWG,
                 float* __restrict__ CC, float* __restrict__ CJW) {
    int bh = blockIdx.x;
    int lane = threadIdx.x;
    const float* src = GLOG + (size_t)bh * L_;
    const float* lw  = LWG  + (size_t)bh * L_;
    float* dst  = CC  + (size_t)bh * L_;
    float* dstw = CJW + (size_t)bh * L_;
    float running = 0.f;
    for (int base = 0; base < L_; base += 64) {
        float v = src[base + lane];
#pragma unroll
        for (int off = 1; off < 64; off <<= 1) {
            float u = __shfl_up(v, off, 64);
            if (lane >= off) v += u;
        }
        float c = running + v;
        dst[base + lane]  = c;
        dstw[base + lane] = c - lw[base + lane];
        running += __shfl(v, 63, 64);
    }
}

// ---------------------------------------------------------------------------
// bf16 MFMA GEMM: C[M,N] = A[M,K] @ W[N,K]^T, 128x128 tile, BK=64, 4 waves.
// mode 1: f32 row-major out.
// mode 2: QKV special: col<2048 -> phi + bf16 row-major (stride QKV_N);
//         col>=2048 -> V, written TRANSPOSED to Vtb[(b*16+h)*64+dh][2048]
// ---------------------------------------------------------------------------
__global__ __launch_bounds__(256)
void gemm_mfma_bt(const u16* __restrict__ A, const u16* __restrict__ Bw,
                  void* __restrict__ Cout, u16* __restrict__ Vtb,
                  int M, int N, int K, int mode) {
    __shared__ u16 As[8192];   // chunk-major [8 cc][128 row][8]
    __shared__ u16 Bs[8192];
    int t = threadIdx.x, lane = t & 63;
    int w = t >> 6, wm = w >> 1, wn = w & 1;
    int l15 = lane & 15, l4 = lane >> 4;
    int m0 = blockIdx.x * 128, n0 = blockIdx.y * 128;

    f32x4 zz = {0.f, 0.f, 0.f, 0.f};
    f32x4 acc[4][4];
#pragma unroll
    for (int m = 0; m < 4; m++)
#pragma unroll
        for (int n = 0; n < 4; n++) acc[m][n] = zz;

    for (int k0 = 0; k0 < K; k0 += 64) {
#pragma unroll
        for (int i = 0; i < 4; i++) {
            int c = i * 256 + t;
            int row = c & 127, cc = c >> 7;
            async16(&As[c * 8], A  + (size_t)(m0 + row) * K + k0 + cc * 8);
            async16(&Bs[c * 8], Bw + (size_t)(n0 + row) * K + k0 + cc * 8);
        }
        __syncthreads();

        bf16x8 af[4][2], bfr[4][2];
#pragma unroll
        for (int ks = 0; ks < 2; ks++) {
#pragma unroll
            for (int m = 0; m < 4; m++)
                af[m][ks] = *(const bf16x8*)&As[(l4 + 4 * ks) * 1024 + (wm * 64 + m * 16 + l15) * 8];
#pragma unroll
            for (int n = 0; n < 4; n++)
                bfr[n][ks] = *(const bf16x8*)&Bs[(l4 + 4 * ks) * 1024 + (wn * 64 + n * 16 + l15) * 8];
        }
#pragma unroll
        for (int m = 0; m < 4; m++)
#pragma unroll
            for (int n = 0; n < 4; n++) {
                acc[m][n] = __builtin_amdgcn_mfma_f32_16x16x32_bf16(af[m][0], bfr[n][0], acc[m][n], 0, 0, 0);
                acc[m][n] = __builtin_amdgcn_mfma_f32_16x16x32_bf16(af[m][1], bfr[n][1], acc[m][n], 0, 0, 0);
            }
        __syncthreads();
    }

#pragma unroll
    for (int m = 0; m < 4; m++)
#pragma unroll
        for (int n = 0; n < 4; n++) {
            int colb = n0 + wn * 64 + n * 16 + l15;
            int rowb = m0 + wm * 64 + m * 16 + l4 * 4;
            if (mode == 1) {
#pragma unroll
                for (int r = 0; r < 4; r++)
                    ((float*)Cout)[(size_t)(rowb + r) * N + colb] = acc[m][n][r];
            } else {
                if (colb < 2048) {
#pragma unroll
                    for (int r = 0; r < 4; r++) {
                        float c = acc[m][n][r];
                        c = (c > 0.f) ? (c + 1.f) : __expf(c);
                        ((u16*)Cout)[(size_t)(rowb + r) * N + colb] = f2bf(c);
                    }
                } else {
                    int vcol = colb - 2048;
                    int bb = rowb >> 11;
                    ushort4 o;
                    o.x = f2bf(acc[m][n][0]); o.y = f2bf(acc[m][n][1]);
                    o.z = f2bf(acc[m][n][2]); o.w = f2bf(acc[m][n][3]);
                    *(ushort4*)&Vtb[((size_t)((bb * 16 + (vcol >> 6)) * 64 + (vcol & 63))) * 2048 + (rowb & 2047)] = o;
                }
            }
        }
}

// ---------------------------------------------------------------------------
// Attention: swapped-QK 32x32x16 MFMA, reg-staged async K/V, raw barriers.
// Block = (b,h,i-tile 64), 2 waves x 32 rows. XCD-pinned bh, heavy-first.
// ---------------------------------------------------------------------------
__global__ __launch_bounds__(128, 2)
void attn_mfma(const u16* __restrict__ QKV, const u16* __restrict__ Vtb,
               const float* __restrict__ CCg, const float* __restrict__ CJWg,
               u16* __restrict__ AOb) {
    __shared__ u16 Ks[2][4096];     // chunk-major [8 cc][64 row][8]
    __shared__ u16 Vs[2][4096];     // chunk-major [8 cc][64 dh][8]
    __shared__ float cjws[2048];

    // XCD-aware decode: same bh -> same XCD (id%8), heavy iT dispatched first
    int id = (int)blockIdx.x;
    int bh = ((id & 7) << 2) | ((id >> 3) & 3);
    int iT = 31 - (id >> 5);
    int b = bh >> 4, h = bh & 15;
    int i0 = iT * 64;
    int t = threadIdx.x, w = t >> 6, lane = t & 63;
    int l31 = lane & 31, hi = lane >> 5;
    int w32 = w * 32;

    // stage CJW for this (b,h) once (async -> drained by prologue sync)
#pragma unroll
    for (int rnd = 0; rnd < 4; rnd++) {
        int c = rnd * 128 + t;
        async16(&cjws[c * 4], CJWg + (size_t)bh * L_ + c * 4);
    }

    // Q fragments + ci straight from global (once per block)
    const u16* qbase = QKV + (size_t)(b * L_ + i0 + w32 + l31) * QKV_N + h * DH;
    bf16x8 qb[4];
#pragma unroll
    for (int ks = 0; ks < 4; ks++)
        qb[ks] = *(const bf16x8*)(qbase + ks * 16 + hi * 8);
    float ci = CCg[(size_t)bh * L_ + i0 + w32 + l31];

    const u16* kbg0 = QKV + 1024 + (size_t)(b * L_) * QKV_N + h * DH;
    const u16* vbg0 = Vtb + (size_t)(bh * 64) * 2048;

    uint4 kreg[4], vreg[4];
    auto STAGE_LOAD = [&](int jt) {
        int j0s = jt * 64;
#pragma unroll
        for (int rnd = 0; rnd < 4; rnd++) {
            int c = rnd * 128 + t;
            int row = c & 63, cc = c >> 6;
            kreg[rnd] = *(const uint4*)(kbg0 + (size_t)(j0s + row) * QKV_N + cc * 8);
        }
#pragma unroll
        for (int rnd = 0; rnd < 4; rnd++) {
            int c = rnd * 128 + t;
            int dh = c & 63, cc = c >> 6;
            vreg[rnd] = *(const uint4*)(vbg0 + (size_t)dh * 2048 + j0s + cc * 8);
        }
    };
    auto STAGE_WRITE = [&](int buf) {
#pragma unroll
        for (int rnd = 0; rnd < 4; rnd++) {
            int c = rnd * 128 + t;
            *(uint4*)&Ks[buf][c * 8] = kreg[rnd];
        }
#pragma unroll
        for (int rnd = 0; rnd < 4; rnd++) {
            int c = rnd * 128 + t;
            *(uint4*)&Vs[buf][c * 8] = vreg[rnd];
        }
    };

    f32x16 z16;
#pragma unroll
    for (int r = 0; r < 16; r++) z16[r] = 0.f;
    f32x16 acc[2];
    acc[0] = z16; acc[1] = z16;
    float dloc = 0.f;

    STAGE_LOAD(0);
    STAGE_WRITE(0);            // compiler inserts vmcnt wait for the regs
    __syncthreads();           // full drain once: tile0 + cjws visible
    if (iT >= 1) STAGE_LOAD(1);

    int cur = 0;
    int lim = w32 + l31;       // local row within the 64-row i-tile
    for (int jt = 0; jt <= iT; ++jt) {
        int j0 = jt * 64;
        bool diag = (jt == iT);

        // ---- QK^T swapped: st[n] = S^T frag, S[j][i], i = l31 ----
        f32x16 st[2];
        st[0] = z16; st[1] = z16;
#pragma unroll
        for (int ks = 0; ks < 4; ks++) {
            bf16x8 k0 = *(const bf16x8*)&Ks[cur][((ks * 2 + hi) * 64 + l31) * 8];
            bf16x8 k1 = *(const bf16x8*)&Ks[cur][((ks * 2 + hi) * 64 + 32 + l31) * 8];
            st[0] = __builtin_amdgcn_mfma_f32_32x32x16_bf16(k0, qb[ks], st[0], 0, 0, 0);
            st[1] = __builtin_amdgcn_mfma_f32_32x32x16_bf16(k1, qb[ks], st[1], 0, 0, 0);
        }

        // write next tile into the other buffer; then issue loads for jt+2
        if (jt < iT) STAGE_WRITE(cur ^ 1);
        if (jt + 1 < iT) STAGE_LOAD(jt + 2);

        // ---- decay/gate/mask in-register, pack to bf16 quads ----
        unsigned pk[2][4][2];
#pragma unroll
        for (int n = 0; n < 2; n++) {
#pragma unroll
            for (int rq = 0; rq < 4; rq++) {
                float4 cj4 = *(const float4*)&cjws[j0 + n * 32 + rq * 8 + hi * 4];
                float e0 = st[n][rq * 4 + 0] * fexp2(ci - cj4.x);
                float e1 = st[n][rq * 4 + 1] * fexp2(ci - cj4.y);
                float e2 = st[n][rq * 4 + 2] * fexp2(ci - cj4.z);
                float e3 = st[n][rq * 4 + 3] * fexp2(ci - cj4.w);
                if (diag) {
                    int jb = n * 32 + rq * 8 + hi * 4;
                    e0 = (jb + 0 <= lim) ? e0 : 0.f;
                    e1 = (jb + 1 <= lim) ? e1 : 0.f;
                    e2 = (jb + 2 <= lim) ? e2 : 0.f;
                    e3 = (jb + 3 <= lim) ? e3 : 0.f;
                }
                dloc += (e0 + e1) + (e2 + e3);
                asm("v_cvt_pk_bf16_f32 %0, %1, %2" : "=v"(pk[n][rq][0]) : "v"(e0), "v"(e1));
                asm("v_cvt_pk_bf16_f32 %0, %1, %2" : "=v"(pk[n][rq][1]) : "v"(e2), "v"(e3));
            }
        }

        // ---- assemble PV A-frags via permlane32_swap, multiply against V ----
#pragma unroll
        for (int wi = 0; wi < 4; wi++) {
            int n = wi >> 1, qA = 2 * (wi & 1), qB = qA + 1;
            unsigned a0 = pk[n][qA][0], b0 = pk[n][qB][0];
            unsigned a1 = pk[n][qA][1], b1 = pk[n][qB][1];
            asm volatile("v_permlane32_swap_b32 %0, %1" : "+v"(a0), "+v"(b0));
            asm volatile("v_permlane32_swap_b32 %0, %1" : "+v"(a1), "+v"(b1));
            union { unsigned u[4]; bf16x8 v; } aw;
            aw.u[0] = a0; aw.u[1] = a1; aw.u[2] = b0; aw.u[3] = b1;
#pragma unroll
            for (int m = 0; m < 2; m++) {
                bf16x8 vb = *(const bf16x8*)&Vs[cur][((wi * 2 + hi) * 64 + m * 32 + l31) * 8];
                acc[m] = __builtin_amdgcn_mfma_f32_32x32x16_bf16(aw.v, vb, acc[m], 0, 0, 0);
            }
        }

        if (jt < iT) {
            __builtin_amdgcn_sched_barrier(0);
            asm volatile("s_waitcnt lgkmcnt(0)" ::: "memory");
            __builtin_amdgcn_s_barrier();          // no vmcnt drain: prefetch stays in flight
            __builtin_amdgcn_sched_barrier(0);
        }
        cur ^= 1;
    }

    // denominator: other hi-half holds the rest of row i = l31
    float dtot = dloc + __shfl_xor(dloc, 32, 64);
    float dr[16];
#pragma unroll
    for (int r = 0; r < 16; r++) {
        int il = (r & 3) + 8 * (r >> 2) + 4 * hi;
        dr[r] = __shfl(dtot, il, 64);
    }
#pragma unroll
    for (int m = 0; m < 2; m++)
#pragma unroll
        for (int r = 0; r < 16; r++) {
            int il = (r & 3) + 8 * (r >> 2) + 4 * hi;
            float o = acc[m][r] / (dr[r] + 1e-6f);
            int ig = i0 + w32 + il;
            AOb[(size_t)(b * L_ + ig) * D_ + h * DH + m * 32 + l31] = f2bf(o);
        }
}

// ---------------------------------------------------------------------------
extern "C" void kernel_launch(void* const* d_in, const int* in_sizes, int n_in,
                              void* d_out, int out_size, void* d_ws, size_t ws_size,
                              hipStream_t stream) {
    const float* x  = (const float*)d_in[0];
    const float* Wq = (const float*)d_in[1];
    const float* Wk = (const float*)d_in[2];
    const float* Wv = (const float*)d_in[3];
    const float* Wo = (const float*)d_in[4];
    const float* Ww = (const float*)d_in[5];
    const float* bw = (const float*)d_in[6];
    const float* We = (const float*)d_in[7];
    const float* be = (const float*)d_in[8];
    float* out = (float*)d_out;

    char* wsb = (char*)d_ws;
    u16* xb   = (u16*)(wsb);                        // 8MB
    u16* Wcat = (u16*)(wsb + ((size_t)8  << 20));   // 8MB  [Wq;Wk;Wv;Wo] bf16
    u16* QKV  = (u16*)(wsb + ((size_t)16 << 20));   // 24MB [4096][3072] (V cols unused)
    u16* Vtb  = (u16*)(wsb + ((size_t)40 << 20));   // 8MB  [B*H*64][2048]
    u16* AOb  = (u16*)(wsb + ((size_t)48 << 20));   // 8MB  [4096][1024]
    float* GLOG = (float*)(wsb + ((size_t)56 << 20));
    float* LWG  = GLOG + 65536;
    float* CC   = LWG  + 65536;
    float* CJW  = CC   + 65536;

    gates_castx<<<ML / 16, 256, 0, stream>>>(x, Ww, bw, We, be, xb, GLOG, LWG);
    cast_w4<<<4096, 256, 0, stream>>>(Wq, Wk, Wv, Wo, Wcat);
    scan_kernel<<<B_ * H_, 64, 0, stream>>>(GLOG, LWG, CC, CJW);

    // fused Q,K,V projection: phi on Q,K; V written transposed into Vtb
    gemm_mfma_bt<<<dim3(ML / 128, QKV_N / 128), 256, 0, stream>>>(
        xb, Wcat, QKV, Vtb, ML, QKV_N, D_, 2);

    attn_mfma<<<dim3(32 * 32), 128, 0, stream>>>(QKV, Vtb, CC, CJW, AOb);

    gemm_mfma_bt<<<dim3(ML / 128, D_ / 128), 256, 0, stream>>>(
        AOb, Wcat + (size_t)3072 * 1024, out, Vtb, ML, D_, D_, 1);
}

// Round 5
// 205.106 us; speedup vs baseline: 1.2855x; 1.2855x over previous
//
#include <hip/hip_runtime.h>
#include <hip/hip_bf16.h>
#include <math.h>

#define B_ 2
#define L_ 2048
#define D_ 1024
#define H_ 16
#define DH 64
#define ML (B_*L_)      // 4096
#define QKV_N 3072

typedef __attribute__((ext_vector_type(8)))  short bf16x8;
typedef __attribute__((ext_vector_type(4)))  float f32x4;
typedef __attribute__((ext_vector_type(16))) float f32x16;
typedef unsigned short u16;

__device__ __forceinline__ u16 f2bf(float f) {
    union { float f; unsigned u; } v; v.f = f;
    unsigned r = (v.u + 0x7FFFu + ((v.u >> 16) & 1u)) >> 16;
    return (u16)r;
}

__device__ __forceinline__ float fexp2(float x) {
    float r; asm("v_exp_f32 %0, %1" : "=v"(r) : "v"(x)); return r;
}

// async global->LDS, 16B per lane (lds dest must be linear base + lane*16).
__device__ __forceinline__ void async16(void* lds, const void* g) {
    __builtin_amdgcn_global_load_lds(
        (__attribute__((address_space(1))) unsigned int*)g,
        (__attribute__((address_space(3))) unsigned int*)lds,
        16, 0, 0);
}

// ---------------------------------------------------------------------------
// pack Wq,Wk,Wv,Wo (each 1M elements) into Wcat bf16 [4096][1024]
// ---------------------------------------------------------------------------
__global__ __launch_bounds__(256)
void cast_w4(const float* __restrict__ Wq, const float* __restrict__ Wk,
             const float* __restrict__ Wv, const float* __restrict__ Wo,
             u16* __restrict__ dst) {
    int i = (blockIdx.x * 256 + threadIdx.x) * 4;     // 0..4M-1
    int sel = i >> 20;
    const float* s = sel == 0 ? Wq : sel == 1 ? Wk : sel == 2 ? Wv : Wo;
    float4 v = *(const float4*)(s + (i & 1048575));
    ushort4 o;
    o.x = f2bf(v.x); o.y = f2bf(v.y); o.z = f2bf(v.z); o.w = f2bf(v.w);
    *(ushort4*)(dst + i) = o;
}

// ---------------------------------------------------------------------------
// Gates + x->bf16 cast fused. Block = 16 rows x 32 gates. Log2-domain out:
// LWG  = log2(sigmoid(x.Ww + bw)); GLOG = log2((1-sigmoid(x.We+be))*0.95+1e-8)
// ---------------------------------------------------------------------------
__global__ __launch_bounds__(256)
void gates_castx(const float* __restrict__ x,
                 const float* __restrict__ Ww, const float* __restrict__ bw,
                 const float* __restrict__ We, const float* __restrict__ be,
                 u16* __restrict__ xb,
                 float* __restrict__ GLOG, float* __restrict__ LWG) {
    __shared__ float xs[16][132];
    __shared__ float ws[32][132];
    int r0 = blockIdx.x * 16;
    int t = threadIdx.x;
    int r = t >> 4, h = t & 15;
    float sw = 0.f, se = 0.f;
    for (int k0 = 0; k0 < D_; k0 += 128) {
#pragma unroll
        for (int i = 0; i < 2; i++) {
            int c = (i * 256 + t) * 4;
            int rr = c >> 7, kk = c & 127;
            float4 xv = *(const float4*)&x[(size_t)(r0 + rr) * D_ + k0 + kk];
            *(float4*)&xs[rr][kk] = xv;
            ushort4 o;
            o.x = f2bf(xv.x); o.y = f2bf(xv.y); o.z = f2bf(xv.z); o.w = f2bf(xv.w);
            *(ushort4*)&xb[(size_t)(r0 + rr) * D_ + k0 + kk] = o;
        }
#pragma unroll
        for (int i = 0; i < 4; i++) {
            int c = (i * 256 + t) * 4;
            int rr = c >> 7, kk = c & 127;
            const float* src = rr < 16 ? &Ww[(size_t)rr * D_ + k0 + kk]
                                       : &We[(size_t)(rr - 16) * D_ + k0 + kk];
            *(float4*)&ws[rr][kk] = *(const float4*)src;
        }
        __syncthreads();
#pragma unroll
        for (int kk = 0; kk < 128; kk += 4) {
            float4 xv = *(const float4*)&xs[r][kk];
            float4 w1 = *(const float4*)&ws[h][kk];
            float4 w2 = *(const float4*)&ws[16 + h][kk];
            sw += xv.x * w1.x + xv.y * w1.y + xv.z * w1.z + xv.w * w1.w;
            se += xv.x * w2.x + xv.y * w2.y + xv.z * w2.z + xv.w * w2.w;
        }
        __syncthreads();
    }
    int row = r0 + r; int b = row >> 11, l = row & 2047;
    float wgv = 1.f / (1.f + __expf(-(sw + bw[h])));
    float egv = 1.f / (1.f + __expf(-(se + be[h])));
    size_t idx = ((size_t)(b * H_ + h)) * L_ + l;
    LWG[idx]  = __log2f(wgv);
    GLOG[idx] = __log2f((1.f - egv) * 0.95f + 1e-8f);
}

// ---------------------------------------------------------------------------
// Inclusive scan per (b,h): CC = cumsum(GLOG); CJW = CC - LWG   (log2 domain)
// ---------------------------------------------------------------------------
__global__ __launch_bounds__(64)
void scan_kernel(const float* __restrict__ GLOG, const float* __restrict__ LWG,
                 float* __restrict__ CC, float* __restrict__ CJW) {
    int bh = blockIdx.x;
    int lane = threadIdx.x;
    const float* src = GLOG + (size_t)bh * L_;
    const float* lw  = LWG  + (size_t)bh * L_;
    float* dst  = CC  + (size_t)bh * L_;
    float* dstw = CJW + (size_t)bh * L_;
    float running = 0.f;
    for (int base = 0; base < L_; base += 64) {
        float v = src[base + lane];
#pragma unroll
        for (int off = 1; off < 64; off <<= 1) {
            float u = __shfl_up(v, off, 64);
            if (lane >= off) v += u;
        }
        float c = running + v;
        dst[base + lane]  = c;
        dstw[base + lane] = c - lw[base + lane];
        running += __shfl(v, 63, 64);
    }
}

// ---------------------------------------------------------------------------
// bf16 MFMA GEMM: C[M,N] = A[M,K] @ W[N,K]^T, 128x128 tile, BK=64, 4 waves.
// mode 1: f32 row-major out.
// mode 2: QKV special: col<2048 -> phi + bf16 row-major (stride QKV_N);
//         col>=2048 -> V, written TRANSPOSED to Vtb[(b*16+h)*64+dh][2048]
// ---------------------------------------------------------------------------
__global__ __launch_bounds__(256)
void gemm_mfma_bt(const u16* __restrict__ A, const u16* __restrict__ Bw,
                  void* __restrict__ Cout, u16* __restrict__ Vtb,
                  int M, int N, int K, int mode) {
    __shared__ u16 As[8192];   // chunk-major [8 cc][128 row][8]
    __shared__ u16 Bs[8192];
    int t = threadIdx.x, lane = t & 63;
    int w = t >> 6, wm = w >> 1, wn = w & 1;
    int l15 = lane & 15, l4 = lane >> 4;
    int m0 = blockIdx.x * 128, n0 = blockIdx.y * 128;

    f32x4 zz = {0.f, 0.f, 0.f, 0.f};
    f32x4 acc[4][4];
#pragma unroll
    for (int m = 0; m < 4; m++)
#pragma unroll
        for (int n = 0; n < 4; n++) acc[m][n] = zz;

    for (int k0 = 0; k0 < K; k0 += 64) {
#pragma unroll
        for (int i = 0; i < 4; i++) {
            int c = i * 256 + t;
            int row = c & 127, cc = c >> 7;
            async16(&As[c * 8], A  + (size_t)(m0 + row) * K + k0 + cc * 8);
            async16(&Bs[c * 8], Bw + (size_t)(n0 + row) * K + k0 + cc * 8);
        }
        __syncthreads();

        bf16x8 af[4][2], bfr[4][2];
#pragma unroll
        for (int ks = 0; ks < 2; ks++) {
#pragma unroll
            for (int m = 0; m < 4; m++)
                af[m][ks] = *(const bf16x8*)&As[(l4 + 4 * ks) * 1024 + (wm * 64 + m * 16 + l15) * 8];
#pragma unroll
            for (int n = 0; n < 4; n++)
                bfr[n][ks] = *(const bf16x8*)&Bs[(l4 + 4 * ks) * 1024 + (wn * 64 + n * 16 + l15) * 8];
        }
#pragma unroll
        for (int m = 0; m < 4; m++)
#pragma unroll
            for (int n = 0; n < 4; n++) {
                acc[m][n] = __builtin_amdgcn_mfma_f32_16x16x32_bf16(af[m][0], bfr[n][0], acc[m][n], 0, 0, 0);
                acc[m][n] = __builtin_amdgcn_mfma_f32_16x16x32_bf16(af[m][1], bfr[n][1], acc[m][n], 0, 0, 0);
            }
        __syncthreads();
    }

#pragma unroll
    for (int m = 0; m < 4; m++)
#pragma unroll
        for (int n = 0; n < 4; n++) {
            int colb = n0 + wn * 64 + n * 16 + l15;
            int rowb = m0 + wm * 64 + m * 16 + l4 * 4;
            if (mode == 1) {
#pragma unroll
                for (int r = 0; r < 4; r++)
                    ((float*)Cout)[(size_t)(rowb + r) * N + colb] = acc[m][n][r];
            } else {
                if (colb < 2048) {
#pragma unroll
                    for (int r = 0; r < 4; r++) {
                        float c = acc[m][n][r];
                        c = (c > 0.f) ? (c + 1.f) : __expf(c);
                        ((u16*)Cout)[(size_t)(rowb + r) * N + colb] = f2bf(c);
                    }
                } else {
                    int vcol = colb - 2048;
                    int bb = rowb >> 11;
                    ushort4 o;
                    o.x = f2bf(acc[m][n][0]); o.y = f2bf(acc[m][n][1]);
                    o.z = f2bf(acc[m][n][2]); o.w = f2bf(acc[m][n][3]);
                    *(ushort4*)&Vtb[((size_t)((bb * 16 + (vcol >> 6)) * 64 + (vcol & 63))) * 2048 + (rowb & 2047)] = o;
                }
            }
        }
}

// ---------------------------------------------------------------------------
// Attention: swapped-QK 32x32x16 MFMA, global_load_lds dbuf staging,
// XCD-pinned bh (id%8 -> XCD), heavy-first iT. 2 waves x 32 Q-rows.
// ---------------------------------------------------------------------------
__global__ __launch_bounds__(128, 2)
void attn_mfma(const u16* __restrict__ QKV, const u16* __restrict__ Vtb,
               const float* __restrict__ CCg, const float* __restrict__ CJWg,
               u16* __restrict__ AOb) {
    __shared__ u16 Ks[2][4096];     // chunk-major [8 cc][64 row][8]
    __shared__ u16 Vs[2][4096];     // chunk-major [8 cc][64 dh][8]
    __shared__ float cjws[2048];

    // XCD-aware decode: same bh -> same XCD (id%8), heavy iT dispatched first
    int id = (int)blockIdx.x;
    int bh = ((id & 7) << 2) | ((id >> 3) & 3);
    int iT = 31 - (id >> 5);
    int b = bh >> 4, h = bh & 15;
    int i0 = iT * 64;
    int t = threadIdx.x, w = t >> 6, lane = t & 63;
    int l31 = lane & 31, hi = lane >> 5;
    int w32 = w * 32;

    // stage CJW for this (b,h) once (drained by prologue syncthreads)
#pragma unroll
    for (int rnd = 0; rnd < 4; rnd++) {
        int c = rnd * 128 + t;
        async16(&cjws[c * 4], CJWg + (size_t)bh * L_ + c * 4);
    }

    // Q fragments + ci straight from global (once per block)
    const u16* qbase = QKV + (size_t)(b * L_ + i0 + w32 + l31) * QKV_N + h * DH;
    bf16x8 qb[4];
#pragma unroll
    for (int ks = 0; ks < 4; ks++)
        qb[ks] = *(const bf16x8*)(qbase + ks * 16 + hi * 8);
    float ci = CCg[(size_t)bh * L_ + i0 + w32 + l31];

    const u16* kbg0 = QKV + 1024 + (size_t)(b * L_) * QKV_N + h * DH;
    const u16* vbg0 = Vtb + (size_t)(bh * 64) * 2048;

    auto STAGE = [&](int buf, int jt) {
        int j0s = jt * 64;
#pragma unroll
        for (int rnd = 0; rnd < 4; rnd++) {
            int c = rnd * 128 + t;
            int row = c & 63, cc = c >> 6;
            async16(&Ks[buf][c * 8], kbg0 + (size_t)(j0s + row) * QKV_N + cc * 8);
        }
#pragma unroll
        for (int rnd = 0; rnd < 4; rnd++) {
            int c = rnd * 128 + t;
            int dh = c & 63, cc = c >> 6;
            async16(&Vs[buf][c * 8], vbg0 + (size_t)dh * 2048 + j0s + cc * 8);
        }
    };

    f32x16 z16;
#pragma unroll
    for (int r = 0; r < 16; r++) z16[r] = 0.f;
    f32x16 acc[2];
    acc[0] = z16; acc[1] = z16;
    float dloc = 0.f;

    STAGE(0, 0);
    __syncthreads();   // drains vmcnt: tile 0 + cjws ready

    int cur = 0;
    int lim = w32 + l31;       // local row within the 64-row i-tile
    for (int jt = 0; jt <= iT; ++jt) {
        int j0 = jt * 64;
        bool diag = (jt == iT);
        if (jt < iT) STAGE(cur ^ 1, jt + 1);   // prefetch overlaps compute

        // ---- QK^T swapped: st[n] = S^T frag, S[j][i], i = l31 ----
        f32x16 st[2];
        st[0] = z16; st[1] = z16;
#pragma unroll
        for (int ks = 0; ks < 4; ks++) {
            bf16x8 k0 = *(const bf16x8*)&Ks[cur][((ks * 2 + hi) * 64 + l31) * 8];
            bf16x8 k1 = *(const bf16x8*)&Ks[cur][((ks * 2 + hi) * 64 + 32 + l31) * 8];
            st[0] = __builtin_amdgcn_mfma_f32_32x32x16_bf16(k0, qb[ks], st[0], 0, 0, 0);
            st[1] = __builtin_amdgcn_mfma_f32_32x32x16_bf16(k1, qb[ks], st[1], 0, 0, 0);
        }

        // ---- decay/gate/mask in-register, pack to bf16 quads ----
        unsigned pk[2][4][2];
#pragma unroll
        for (int n = 0; n < 2; n++) {
#pragma unroll
            for (int rq = 0; rq < 4; rq++) {
                float4 cj4 = *(const float4*)&cjws[j0 + n * 32 + rq * 8 + hi * 4];
                float e0 = st[n][rq * 4 + 0] * fexp2(ci - cj4.x);
                float e1 = st[n][rq * 4 + 1] * fexp2(ci - cj4.y);
                float e2 = st[n][rq * 4 + 2] * fexp2(ci - cj4.z);
                float e3 = st[n][rq * 4 + 3] * fexp2(ci - cj4.w);
                if (diag) {
                    int jb = n * 32 + rq * 8 + hi * 4;
                    e0 = (jb + 0 <= lim) ? e0 : 0.f;
                    e1 = (jb + 1 <= lim) ? e1 : 0.f;
                    e2 = (jb + 2 <= lim) ? e2 : 0.f;
                    e3 = (jb + 3 <= lim) ? e3 : 0.f;
                }
                dloc += (e0 + e1) + (e2 + e3);
                asm("v_cvt_pk_bf16_f32 %0, %1, %2" : "=v"(pk[n][rq][0]) : "v"(e0), "v"(e1));
                asm("v_cvt_pk_bf16_f32 %0, %1, %2" : "=v"(pk[n][rq][1]) : "v"(e2), "v"(e3));
            }
        }

        // ---- assemble PV A-frags via permlane32_swap, multiply against V ----
#pragma unroll
        for (int wi = 0; wi < 4; wi++) {
            int n = wi >> 1, qA = 2 * (wi & 1), qB = qA + 1;
            unsigned a0 = pk[n][qA][0], b0 = pk[n][qB][0];
            unsigned a1 = pk[n][qA][1], b1 = pk[n][qB][1];
            asm volatile("v_permlane32_swap_b32 %0, %1" : "+v"(a0), "+v"(b0));
            asm volatile("v_permlane32_swap_b32 %0, %1" : "+v"(a1), "+v"(b1));
            union { unsigned u[4]; bf16x8 v; } aw;
            aw.u[0] = a0; aw.u[1] = a1; aw.u[2] = b0; aw.u[3] = b1;
#pragma unroll
            for (int m = 0; m < 2; m++) {
                bf16x8 vb = *(const bf16x8*)&Vs[cur][((wi * 2 + hi) * 64 + m * 32 + l31) * 8];
                acc[m] = __builtin_amdgcn_mfma_f32_32x32x16_bf16(aw.v, vb, acc[m], 0, 0, 0);
            }
        }

        __syncthreads();   // drains vmcnt: next tile staged, cur reads done
        cur ^= 1;
    }

    // denominator: other hi-half holds the rest of row i = l31
    float dtot = dloc + __shfl_xor(dloc, 32, 64);
    float dr[16];
#pragma unroll
    for (int r = 0; r < 16; r++) {
        int il = (r & 3) + 8 * (r >> 2) + 4 * hi;
        dr[r] = __shfl(dtot, il, 64);
    }
#pragma unroll
    for (int m = 0; m < 2; m++)
#pragma unroll
        for (int r = 0; r < 16; r++) {
            int il = (r & 3) + 8 * (r >> 2) + 4 * hi;
            float o = acc[m][r] / (dr[r] + 1e-6f);
            int ig = i0 + w32 + il;
            AOb[(size_t)(b * L_ + ig) * D_ + h * DH + m * 32 + l31] = f2bf(o);
        }
}

// ---------------------------------------------------------------------------
extern "C" void kernel_launch(void* const* d_in, const int* in_sizes, int n_in,
                              void* d_out, int out_size, void* d_ws, size_t ws_size,
                              hipStream_t stream) {
    const float* x  = (const float*)d_in[0];
    const float* Wq = (const float*)d_in[1];
    const float* Wk = (const float*)d_in[2];
    const float* Wv = (const float*)d_in[3];
    const float* Wo = (const float*)d_in[4];
    const float* Ww = (const float*)d_in[5];
    const float* bw = (const float*)d_in[6];
    const float* We = (const float*)d_in[7];
    const float* be = (const float*)d_in[8];
    float* out = (float*)d_out;

    char* wsb = (char*)d_ws;
    u16* xb   = (u16*)(wsb);                        // 8MB
    u16* Wcat = (u16*)(wsb + ((size_t)8  << 20));   // 8MB  [Wq;Wk;Wv;Wo] bf16
    u16* QKV  = (u16*)(wsb + ((size_t)16 << 20));   // 24MB [4096][3072] (V cols unused)
    u16* Vtb  = (u16*)(wsb + ((size_t)40 << 20));   // 8MB  [B*H*64][2048]
    u16* AOb  = (u16*)(wsb + ((size_t)48 << 20));   // 8MB  [4096][1024]
    float* GLOG = (float*)(wsb + ((size_t)56 << 20));
    float* LWG  = GLOG + 65536;
    float* CC   = LWG  + 65536;
    float* CJW  = CC   + 65536;

    gates_castx<<<ML / 16, 256, 0, stream>>>(x, Ww, bw, We, be, xb, GLOG, LWG);
    cast_w4<<<4096, 256, 0, stream>>>(Wq, Wk, Wv, Wo, Wcat);
    scan_kernel<<<B_ * H_, 64, 0, stream>>>(GLOG, LWG, CC, CJW);

    // fused Q,K,V projection: phi on Q,K; V written transposed into Vtb
    gemm_mfma_bt<<<dim3(ML / 128, QKV_N / 128), 256, 0, stream>>>(
        xb, Wcat, QKV, Vtb, ML, QKV_N, D_, 2);

    attn_mfma<<<dim3(32 * 32), 128, 0, stream>>>(QKV, Vtb, CC, CJW, AOb);

    gemm_mfma_bt<<<dim3(ML / 128, D_ / 128), 256, 0, stream>>>(
        AOb, Wcat + (size_t)3072 * 1024, out, Vtb, ML, D_, D_, 1);
}

// Round 6
// 159.580 us; speedup vs baseline: 1.6522x; 1.2853x over previous
//
#include <hip/hip_runtime.h>
#include <hip/hip_bf16.h>
#include <math.h>

#define B_ 2
#define L_ 2048
#define D_ 1024
#define H_ 16
#define DH 64
#define ML (B_*L_)      // 4096
#define QKV_N 3072

typedef __attribute__((ext_vector_type(8)))  short bf16x8;
typedef __attribute__((ext_vector_type(4)))  float f32x4;
typedef __attribute__((ext_vector_type(16))) float f32x16;
typedef unsigned short u16;

__device__ __forceinline__ u16 f2bf(float f) {
    union { float f; unsigned u; } v; v.f = f;
    unsigned r = (v.u + 0x7FFFu + ((v.u >> 16) & 1u)) >> 16;
    return (u16)r;
}

__device__ __forceinline__ float fexp2(float x) {
    float r; asm("v_exp_f32 %0, %1" : "=v"(r) : "v"(x)); return r;
}

// async global->LDS, 16B per lane (lds dest must be linear base + lane*16).
__device__ __forceinline__ void async16(void* lds, const void* g) {
    __builtin_amdgcn_global_load_lds(
        (__attribute__((address_space(1))) unsigned int*)g,
        (__attribute__((address_space(3))) unsigned int*)lds,
        16, 0, 0);
}

// ---------------------------------------------------------------------------
// pack Wq,Wk,Wv,Wo (each 1M elements) into Wcat bf16 [4096][1024]
// ---------------------------------------------------------------------------
__global__ __launch_bounds__(256)
void cast_w4(const float* __restrict__ Wq, const float* __restrict__ Wk,
             const float* __restrict__ Wv, const float* __restrict__ Wo,
             u16* __restrict__ dst) {
    int i = (blockIdx.x * 256 + threadIdx.x) * 4;     // 0..4M-1
    int sel = i >> 20;
    const float* s = sel == 0 ? Wq : sel == 1 ? Wk : sel == 2 ? Wv : Wo;
    float4 v = *(const float4*)(s + (i & 1048575));
    ushort4 o;
    o.x = f2bf(v.x); o.y = f2bf(v.y); o.z = f2bf(v.z); o.w = f2bf(v.w);
    *(ushort4*)(dst + i) = o;
}

// ---------------------------------------------------------------------------
// Gates + x->bf16 cast fused. Block = 16 rows x 32 gates. Log2-domain out:
// LWG  = log2(sigmoid(x.Ww + bw)); GLOG = log2((1-sigmoid(x.We+be))*0.95+1e-8)
// ---------------------------------------------------------------------------
__global__ __launch_bounds__(256)
void gates_castx(const float* __restrict__ x,
                 const float* __restrict__ Ww, const float* __restrict__ bw,
                 const float* __restrict__ We, const float* __restrict__ be,
                 u16* __restrict__ xb,
                 float* __restrict__ GLOG, float* __restrict__ LWG) {
    __shared__ float xs[16][132];
    __shared__ float ws[32][132];
    int r0 = blockIdx.x * 16;
    int t = threadIdx.x;
    int r = t >> 4, h = t & 15;
    float sw = 0.f, se = 0.f;
    for (int k0 = 0; k0 < D_; k0 += 128) {
#pragma unroll
        for (int i = 0; i < 2; i++) {
            int c = (i * 256 + t) * 4;
            int rr = c >> 7, kk = c & 127;
            float4 xv = *(const float4*)&x[(size_t)(r0 + rr) * D_ + k0 + kk];
            *(float4*)&xs[rr][kk] = xv;
            ushort4 o;
            o.x = f2bf(xv.x); o.y = f2bf(xv.y); o.z = f2bf(xv.z); o.w = f2bf(xv.w);
            *(ushort4*)&xb[(size_t)(r0 + rr) * D_ + k0 + kk] = o;
        }
#pragma unroll
        for (int i = 0; i < 4; i++) {
            int c = (i * 256 + t) * 4;
            int rr = c >> 7, kk = c & 127;
            const float* src = rr < 16 ? &Ww[(size_t)rr * D_ + k0 + kk]
                                       : &We[(size_t)(rr - 16) * D_ + k0 + kk];
            *(float4*)&ws[rr][kk] = *(const float4*)src;
        }
        __syncthreads();
#pragma unroll
        for (int kk = 0; kk < 128; kk += 4) {
            float4 xv = *(const float4*)&xs[r][kk];
            float4 w1 = *(const float4*)&ws[h][kk];
            float4 w2 = *(const float4*)&ws[16 + h][kk];
            sw += xv.x * w1.x + xv.y * w1.y + xv.z * w1.z + xv.w * w1.w;
            se += xv.x * w2.x + xv.y * w2.y + xv.z * w2.z + xv.w * w2.w;
        }
        __syncthreads();
    }
    int row = r0 + r; int b = row >> 11, l = row & 2047;
    float wgv = 1.f / (1.f + __expf(-(sw + bw[h])));
    float egv = 1.f / (1.f + __expf(-(se + be[h])));
    size_t idx = ((size_t)(b * H_ + h)) * L_ + l;
    LWG[idx]  = __log2f(wgv);
    GLOG[idx] = __log2f((1.f - egv) * 0.95f + 1e-8f);
}

// ---------------------------------------------------------------------------
// Inclusive scan per (b,h): CC = cumsum(GLOG); CJW = CC - LWG   (log2 domain)
// ---------------------------------------------------------------------------
__global__ __launch_bounds__(64)
void scan_kernel(const float* __restrict__ GLOG, const float* __restrict__ LWG,
                 float* __restrict__ CC, float* __restrict__ CJW) {
    int bh = blockIdx.x;
    int lane = threadIdx.x;
    const float* src = GLOG + (size_t)bh * L_;
    const float* lw  = LWG  + (size_t)bh * L_;
    float* dst  = CC  + (size_t)bh * L_;
    float* dstw = CJW + (size_t)bh * L_;
    float running = 0.f;
    for (int base = 0; base < L_; base += 64) {
        float v = src[base + lane];
#pragma unroll
        for (int off = 1; off < 64; off <<= 1) {
            float u = __shfl_up(v, off, 64);
            if (lane >= off) v += u;
        }
        float c = running + v;
        dst[base + lane]  = c;
        dstw[base + lane] = c - lw[base + lane];
        running += __shfl(v, 63, 64);
    }
}

// ---------------------------------------------------------------------------
// bf16 MFMA GEMM: C[M,N] = A[M,K] @ W[N,K]^T, 128x128 tile, BK=64, 4 waves.
// LDS: linear row-major [128][64] bf16 (128B rows), XOR-swizzled source
// (ch_src = ch_stored ^ (row&7)) so staging stays 128B-coalesced and the
// stride-128B fragment reads are conflict-free (T2 / rule 21).
// mode 1: f32 row-major out.
// mode 2: QKV special: col<2048 -> phi + bf16 row-major (stride QKV_N);
//         col>=2048 -> V, written TRANSPOSED to Vtb[(b*16+h)*64+dh][2048]
// ---------------------------------------------------------------------------
__global__ __launch_bounds__(256)
void gemm_mfma_bt(const u16* __restrict__ A, const u16* __restrict__ Bw,
                  void* __restrict__ Cout, u16* __restrict__ Vtb,
                  int M, int N, int K, int mode) {
    __shared__ u16 As[8192];   // [128 row][64 k]  (16KB)
    __shared__ u16 Bs[8192];
    int t = threadIdx.x, lane = t & 63;
    int w = t >> 6, wm = w >> 1, wn = w & 1;
    int l15 = lane & 15, l4 = lane >> 4;
    int m0 = blockIdx.x * 128, n0 = blockIdx.y * 128;

    f32x4 zz = {0.f, 0.f, 0.f, 0.f};
    f32x4 acc[4][4];
#pragma unroll
    for (int m = 0; m < 4; m++)
#pragma unroll
        for (int n = 0; n < 4; n++) acc[m][n] = zz;

    for (int k0 = 0; k0 < K; k0 += 64) {
#pragma unroll
        for (int i = 0; i < 4; i++) {
            int c = i * 256 + t;                 // 16B-chunk index 0..1023
            int row = c >> 3;
            int ch = (c & 7) ^ (row & 7);        // pre-swizzled source chunk
            async16(&As[c * 8], A  + (size_t)(m0 + row) * K + k0 + ch * 8);
            async16(&Bs[c * 8], Bw + (size_t)(n0 + row) * K + k0 + ch * 8);
        }
        __syncthreads();

        bf16x8 af[4][2], bfr[4][2];
#pragma unroll
        for (int ks = 0; ks < 2; ks++) {
#pragma unroll
            for (int m = 0; m < 4; m++) {
                int row = wm * 64 + m * 16 + l15;
                int ch = (l4 + 4 * ks) ^ (row & 7);
                af[m][ks] = *(const bf16x8*)&As[row * 64 + ch * 8];
            }
#pragma unroll
            for (int n = 0; n < 4; n++) {
                int row = wn * 64 + n * 16 + l15;
                int ch = (l4 + 4 * ks) ^ (row & 7);
                bfr[n][ks] = *(const bf16x8*)&Bs[row * 64 + ch * 8];
            }
        }
#pragma unroll
        for (int m = 0; m < 4; m++)
#pragma unroll
            for (int n = 0; n < 4; n++) {
                acc[m][n] = __builtin_amdgcn_mfma_f32_16x16x32_bf16(af[m][0], bfr[n][0], acc[m][n], 0, 0, 0);
                acc[m][n] = __builtin_amdgcn_mfma_f32_16x16x32_bf16(af[m][1], bfr[n][1], acc[m][n], 0, 0, 0);
            }
        __syncthreads();
    }

#pragma unroll
    for (int m = 0; m < 4; m++)
#pragma unroll
        for (int n = 0; n < 4; n++) {
            int colb = n0 + wn * 64 + n * 16 + l15;
            int rowb = m0 + wm * 64 + m * 16 + l4 * 4;
            if (mode == 1) {
#pragma unroll
                for (int r = 0; r < 4; r++)
                    ((float*)Cout)[(size_t)(rowb + r) * N + colb] = acc[m][n][r];
            } else {
                if (colb < 2048) {
#pragma unroll
                    for (int r = 0; r < 4; r++) {
                        float c = acc[m][n][r];
                        c = (c > 0.f) ? (c + 1.f) : __expf(c);
                        ((u16*)Cout)[(size_t)(rowb + r) * N + colb] = f2bf(c);
                    }
                } else {
                    int vcol = colb - 2048;
                    int bb = rowb >> 11;
                    ushort4 o;
                    o.x = f2bf(acc[m][n][0]); o.y = f2bf(acc[m][n][1]);
                    o.z = f2bf(acc[m][n][2]); o.w = f2bf(acc[m][n][3]);
                    *(ushort4*)&Vtb[((size_t)((bb * 16 + (vcol >> 6)) * 64 + (vcol & 63))) * 2048 + (rowb & 2047)] = o;
                }
            }
        }
}

// ---------------------------------------------------------------------------
// Attention: swapped-QK 32x32x16 MFMA, global_load_lds dbuf staging,
// linear+XOR-swizzled LDS tiles, XCD-pinned bh, heavy-first iT.
// ---------------------------------------------------------------------------
__global__ __launch_bounds__(128, 2)
void attn_mfma(const u16* __restrict__ QKV, const u16* __restrict__ Vtb,
               const float* __restrict__ CCg, const float* __restrict__ CJWg,
               u16* __restrict__ AOb) {
    __shared__ u16 Ks[2][4096];     // [64 j][64 k], swizzled
    __shared__ u16 Vs[2][4096];     // [64 dh][64 j], swizzled
    __shared__ float cjws[2048];

    // XCD-aware decode: same bh -> same XCD (id%8), heavy iT dispatched first
    int id = (int)blockIdx.x;
    int bh = ((id & 7) << 2) | ((id >> 3) & 3);
    int iT = 31 - (id >> 5);
    int b = bh >> 4, h = bh & 15;
    int i0 = iT * 64;
    int t = threadIdx.x, w = t >> 6, lane = t & 63;
    int l31 = lane & 31, hi = lane >> 5;
    int w32 = w * 32;

    // stage CJW for this (b,h) once (drained by prologue syncthreads)
#pragma unroll
    for (int rnd = 0; rnd < 4; rnd++) {
        int c = rnd * 128 + t;
        async16(&cjws[c * 4], CJWg + (size_t)bh * L_ + c * 4);
    }

    // Q fragments + ci straight from global (once per block)
    const u16* qbase = QKV + (size_t)(b * L_ + i0 + w32 + l31) * QKV_N + h * DH;
    bf16x8 qb[4];
#pragma unroll
    for (int ks = 0; ks < 4; ks++)
        qb[ks] = *(const bf16x8*)(qbase + ks * 16 + hi * 8);
    float ci = CCg[(size_t)bh * L_ + i0 + w32 + l31];

    const u16* kbg0 = QKV + 1024 + (size_t)(b * L_) * QKV_N + h * DH;
    const u16* vbg0 = Vtb + (size_t)(bh * 64) * 2048;

    auto STAGE = [&](int buf, int jt) {
        int j0s = jt * 64;
#pragma unroll
        for (int rnd = 0; rnd < 4; rnd++) {
            int c = rnd * 128 + t;               // chunk 0..511
            int row = c >> 3;                    // j row
            int ch = (c & 7) ^ (row & 7);        // pre-swizzled k-chunk
            async16(&Ks[buf][c * 8], kbg0 + (size_t)(j0s + row) * QKV_N + ch * 8);
        }
#pragma unroll
        for (int rnd = 0; rnd < 4; rnd++) {
            int c = rnd * 128 + t;
            int dh = c >> 3;
            int jc = (c & 7) ^ (dh & 7);         // pre-swizzled j-chunk
            async16(&Vs[buf][c * 8], vbg0 + (size_t)dh * 2048 + j0s + jc * 8);
        }
    };

    f32x16 z16;
#pragma unroll
    for (int r = 0; r < 16; r++) z16[r] = 0.f;
    f32x16 acc[2];
    acc[0] = z16; acc[1] = z16;
    float dloc = 0.f;

    STAGE(0, 0);
    __syncthreads();   // drains vmcnt: tile 0 + cjws ready

    int cur = 0;
    int lim = w32 + l31;       // local row within the 64-row i-tile
    for (int jt = 0; jt <= iT; ++jt) {
        int j0 = jt * 64;
        bool diag = (jt == iT);
        if (jt < iT) STAGE(cur ^ 1, jt + 1);   // prefetch overlaps compute

        // ---- QK^T swapped: st[n] = S^T frag, S[j][i], i = l31 ----
        f32x16 st[2];
        st[0] = z16; st[1] = z16;
        int swz = (l31 & 7);
#pragma unroll
        for (int ks = 0; ks < 4; ks++) {
            int ch = (ks * 2 + hi) ^ swz;        // same low-3 bits for l31 and l31+32
            bf16x8 k0 = *(const bf16x8*)&Ks[cur][l31 * 64 + ch * 8];
            bf16x8 k1 = *(const bf16x8*)&Ks[cur][(32 + l31) * 64 + ch * 8];
            st[0] = __builtin_amdgcn_mfma_f32_32x32x16_bf16(k0, qb[ks], st[0], 0, 0, 0);
            st[1] = __builtin_amdgcn_mfma_f32_32x32x16_bf16(k1, qb[ks], st[1], 0, 0, 0);
        }

        // ---- decay/gate/mask in-register, pack to bf16 quads ----
        unsigned pk[2][4][2];
#pragma unroll
        for (int n = 0; n < 2; n++) {
#pragma unroll
            for (int rq = 0; rq < 4; rq++) {
                float4 cj4 = *(const float4*)&cjws[j0 + n * 32 + rq * 8 + hi * 4];
                float e0 = st[n][rq * 4 + 0] * fexp2(ci - cj4.x);
                float e1 = st[n][rq * 4 + 1] * fexp2(ci - cj4.y);
                float e2 = st[n][rq * 4 + 2] * fexp2(ci - cj4.z);
                float e3 = st[n][rq * 4 + 3] * fexp2(ci - cj4.w);
                if (diag) {
                    int jb = n * 32 + rq * 8 + hi * 4;
                    e0 = (jb + 0 <= lim) ? e0 : 0.f;
                    e1 = (jb + 1 <= lim) ? e1 : 0.f;
                    e2 = (jb + 2 <= lim) ? e2 : 0.f;
                    e3 = (jb + 3 <= lim) ? e3 : 0.f;
                }
                dloc += (e0 + e1) + (e2 + e3);
                asm("v_cvt_pk_bf16_f32 %0, %1, %2" : "=v"(pk[n][rq][0]) : "v"(e0), "v"(e1));
                asm("v_cvt_pk_bf16_f32 %0, %1, %2" : "=v"(pk[n][rq][1]) : "v"(e2), "v"(e3));
            }
        }

        // ---- assemble PV A-frags via permlane32_swap, multiply against V ----
#pragma unroll
        for (int wi = 0; wi < 4; wi++) {
            int n = wi >> 1, qA = 2 * (wi & 1), qB = qA + 1;
            unsigned a0 = pk[n][qA][0], b0 = pk[n][qB][0];
            unsigned a1 = pk[n][qA][1], b1 = pk[n][qB][1];
            asm volatile("v_permlane32_swap_b32 %0, %1" : "+v"(a0), "+v"(b0));
            asm volatile("v_permlane32_swap_b32 %0, %1" : "+v"(a1), "+v"(b1));
            union { unsigned u[4]; bf16x8 v; } aw;
            aw.u[0] = a0; aw.u[1] = a1; aw.u[2] = b0; aw.u[3] = b1;
#pragma unroll
            for (int m = 0; m < 2; m++) {
                int dh = m * 32 + l31;
                int jc = (wi * 2 + hi) ^ (dh & 7);
                bf16x8 vb = *(const bf16x8*)&Vs[cur][dh * 64 + jc * 8];
                acc[m] = __builtin_amdgcn_mfma_f32_32x32x16_bf16(aw.v, vb, acc[m], 0, 0, 0);
            }
        }

        __syncthreads();   // drains vmcnt: next tile staged, cur reads done
        cur ^= 1;
    }

    // denominator: other hi-half holds the rest of row i = l31
    float dtot = dloc + __shfl_xor(dloc, 32, 64);
    float dr[16];
#pragma unroll
    for (int r = 0; r < 16; r++) {
        int il = (r & 3) + 8 * (r >> 2) + 4 * hi;
        dr[r] = __shfl(dtot, il, 64);
    }
#pragma unroll
    for (int m = 0; m < 2; m++)
#pragma unroll
        for (int r = 0; r < 16; r++) {
            int il = (r & 3) + 8 * (r >> 2) + 4 * hi;
            float o = acc[m][r] / (dr[r] + 1e-6f);
            int ig = i0 + w32 + il;
            AOb[(size_t)(b * L_ + ig) * D_ + h * DH + m * 32 + l31] = f2bf(o);
        }
}

// ---------------------------------------------------------------------------
extern "C" void kernel_launch(void* const* d_in, const int* in_sizes, int n_in,
                              void* d_out, int out_size, void* d_ws, size_t ws_size,
                              hipStream_t stream) {
    const float* x  = (const float*)d_in[0];
    const float* Wq = (const float*)d_in[1];
    const float* Wk = (const float*)d_in[2];
    const float* Wv = (const float*)d_in[3];
    const float* Wo = (const float*)d_in[4];
    const float* Ww = (const float*)d_in[5];
    const float* bw = (const float*)d_in[6];
    const float* We = (const float*)d_in[7];
    const float* be = (const float*)d_in[8];
    float* out = (float*)d_out;

    char* wsb = (char*)d_ws;
    u16* xb   = (u16*)(wsb);                        // 8MB
    u16* Wcat = (u16*)(wsb + ((size_t)8  << 20));   // 8MB  [Wq;Wk;Wv;Wo] bf16
    u16* QKV  = (u16*)(wsb + ((size_t)16 << 20));   // 24MB [4096][3072] (V cols unused)
    u16* Vtb  = (u16*)(wsb + ((size_t)40 << 20));   // 8MB  [B*H*64][2048]
    u16* AOb  = (u16*)(wsb + ((size_t)48 << 20));   // 8MB  [4096][1024]
    float* GLOG = (float*)(wsb + ((size_t)56 << 20));
    float* LWG  = GLOG + 65536;
    float* CC   = LWG  + 65536;
    float* CJW  = CC   + 65536;

    gates_castx<<<ML / 16, 256, 0, stream>>>(x, Ww, bw, We, be, xb, GLOG, LWG);
    cast_w4<<<4096, 256, 0, stream>>>(Wq, Wk, Wv, Wo, Wcat);
    scan_kernel<<<B_ * H_, 64, 0, stream>>>(GLOG, LWG, CC, CJW);

    // fused Q,K,V projection: phi on Q,K; V written transposed into Vtb
    gemm_mfma_bt<<<dim3(ML / 128, QKV_N / 128), 256, 0, stream>>>(
        xb, Wcat, QKV, Vtb, ML, QKV_N, D_, 2);

    attn_mfma<<<dim3(32 * 32), 128, 0, stream>>>(QKV, Vtb, CC, CJW, AOb);

    gemm_mfma_bt<<<dim3(ML / 128, D_ / 128), 256, 0, stream>>>(
        AOb, Wcat + (size_t)3072 * 1024, out, Vtb, ML, D_, D_, 1);
}

// Round 7
// 152.093 us; speedup vs baseline: 1.7336x; 1.0492x over previous
//
#include <hip/hip_runtime.h>
#include <hip/hip_bf16.h>
#include <math.h>

#define B_ 2
#define L_ 2048
#define D_ 1024
#define H_ 16
#define DH 64
#define ML (B_*L_)      // 4096
#define QKV_N 3072

typedef __attribute__((ext_vector_type(8)))  short bf16x8;
typedef __attribute__((ext_vector_type(4)))  float f32x4;
typedef __attribute__((ext_vector_type(16))) float f32x16;
typedef unsigned short u16;

__device__ __forceinline__ u16 f2bf(float f) {
    union { float f; unsigned u; } v; v.f = f;
    unsigned r = (v.u + 0x7FFFu + ((v.u >> 16) & 1u)) >> 16;
    return (u16)r;
}

__device__ __forceinline__ float fexp2(float x) {
    float r; asm("v_exp_f32 %0, %1" : "=v"(r) : "v"(x)); return r;
}

// async global->LDS, 16B per lane (lds dest must be linear base + lane*16).
__device__ __forceinline__ void async16(void* lds, const void* g) {
    __builtin_amdgcn_global_load_lds(
        (__attribute__((address_space(1))) unsigned int*)g,
        (__attribute__((address_space(3))) unsigned int*)lds,
        16, 0, 0);
}

// ---------------------------------------------------------------------------
// pack Wq,Wk,Wv,Wo (each 1M elements) into Wcat bf16 [4096][1024]
// ---------------------------------------------------------------------------
__global__ __launch_bounds__(256)
void cast_w4(const float* __restrict__ Wq, const float* __restrict__ Wk,
             const float* __restrict__ Wv, const float* __restrict__ Wo,
             u16* __restrict__ dst) {
    int i = (blockIdx.x * 256 + threadIdx.x) * 4;     // 0..4M-1
    int sel = i >> 20;
    const float* s = sel == 0 ? Wq : sel == 1 ? Wk : sel == 2 ? Wv : Wo;
    float4 v = *(const float4*)(s + (i & 1048575));
    ushort4 o;
    o.x = f2bf(v.x); o.y = f2bf(v.y); o.z = f2bf(v.z); o.w = f2bf(v.w);
    *(ushort4*)(dst + i) = o;
}

// ---------------------------------------------------------------------------
// Gates + x->bf16 cast fused. Block = 16 rows x 32 gates. Log2-domain out:
// LWG  = log2(sigmoid(x.Ww + bw)); GLOG = log2((1-sigmoid(x.We+be))*0.95+1e-8)
// ---------------------------------------------------------------------------
__global__ __launch_bounds__(256)
void gates_castx(const float* __restrict__ x,
                 const float* __restrict__ Ww, const float* __restrict__ bw,
                 const float* __restrict__ We, const float* __restrict__ be,
                 u16* __restrict__ xb,
                 float* __restrict__ GLOG, float* __restrict__ LWG) {
    __shared__ float xs[16][132];
    __shared__ float ws[32][132];
    int r0 = blockIdx.x * 16;
    int t = threadIdx.x;
    int r = t >> 4, h = t & 15;
    float sw = 0.f, se = 0.f;
    for (int k0 = 0; k0 < D_; k0 += 128) {
#pragma unroll
        for (int i = 0; i < 2; i++) {
            int c = (i * 256 + t) * 4;
            int rr = c >> 7, kk = c & 127;
            float4 xv = *(const float4*)&x[(size_t)(r0 + rr) * D_ + k0 + kk];
            *(float4*)&xs[rr][kk] = xv;
            ushort4 o;
            o.x = f2bf(xv.x); o.y = f2bf(xv.y); o.z = f2bf(xv.z); o.w = f2bf(xv.w);
            *(ushort4*)&xb[(size_t)(r0 + rr) * D_ + k0 + kk] = o;
        }
#pragma unroll
        for (int i = 0; i < 4; i++) {
            int c = (i * 256 + t) * 4;
            int rr = c >> 7, kk = c & 127;
            const float* src = rr < 16 ? &Ww[(size_t)rr * D_ + k0 + kk]
                                       : &We[(size_t)(rr - 16) * D_ + k0 + kk];
            *(float4*)&ws[rr][kk] = *(const float4*)src;
        }
        __syncthreads();
#pragma unroll
        for (int kk = 0; kk < 128; kk += 4) {
            float4 xv = *(const float4*)&xs[r][kk];
            float4 w1 = *(const float4*)&ws[h][kk];
            float4 w2 = *(const float4*)&ws[16 + h][kk];
            sw += xv.x * w1.x + xv.y * w1.y + xv.z * w1.z + xv.w * w1.w;
            se += xv.x * w2.x + xv.y * w2.y + xv.z * w2.z + xv.w * w2.w;
        }
        __syncthreads();
    }
    int row = r0 + r; int b = row >> 11, l = row & 2047;
    float wgv = 1.f / (1.f + __expf(-(sw + bw[h])));
    float egv = 1.f / (1.f + __expf(-(se + be[h])));
    size_t idx = ((size_t)(b * H_ + h)) * L_ + l;
    LWG[idx]  = __log2f(wgv);
    GLOG[idx] = __log2f((1.f - egv) * 0.95f + 1e-8f);
}

// ---------------------------------------------------------------------------
// Inclusive scan per (b,h): CC = cumsum(GLOG); CJW = CC - LWG   (log2 domain)
// ---------------------------------------------------------------------------
__global__ __launch_bounds__(64)
void scan_kernel(const float* __restrict__ GLOG, const float* __restrict__ LWG,
                 float* __restrict__ CC, float* __restrict__ CJW) {
    int bh = blockIdx.x;
    int lane = threadIdx.x;
    const float* src = GLOG + (size_t)bh * L_;
    const float* lw  = LWG  + (size_t)bh * L_;
    float* dst  = CC  + (size_t)bh * L_;
    float* dstw = CJW + (size_t)bh * L_;
    float running = 0.f;
    for (int base = 0; base < L_; base += 64) {
        float v = src[base + lane];
#pragma unroll
        for (int off = 1; off < 64; off <<= 1) {
            float u = __shfl_up(v, off, 64);
            if (lane >= off) v += u;
        }
        float c = running + v;
        dst[base + lane]  = c;
        dstw[base + lane] = c - lw[base + lane];
        running += __shfl(v, 63, 64);
    }
}

// ---------------------------------------------------------------------------
// bf16 MFMA GEMM: C[M,N] = A[M,K] @ W[N,K]^T, 128x128 tile, BK=64, 4 waves.
// 2-PHASE double-buffered: STAGE(next) issued BEFORE compute(cur); single
// __syncthreads per K-step drains whatever the compute phase didn't cover.
// LDS: linear row-major [128][64] bf16, XOR-swizzled source (T2 / rule 21).
// mode 1: f32 row-major out.
// mode 2: QKV special: col<2048 -> phi + bf16 row-major (stride QKV_N);
//         col>=2048 -> V, written TRANSPOSED to Vtb[(b*16+h)*64+dh][2048]
// ---------------------------------------------------------------------------
__global__ __launch_bounds__(256)
void gemm_mfma_bt(const u16* __restrict__ A, const u16* __restrict__ Bw,
                  void* __restrict__ Cout, u16* __restrict__ Vtb,
                  int M, int N, int K, int mode) {
    __shared__ u16 As[2][8192];   // [128 row][64 k]  (16KB each)
    __shared__ u16 Bs[2][8192];
    int t = threadIdx.x, lane = t & 63;
    int w = t >> 6, wm = w >> 1, wn = w & 1;
    int l15 = lane & 15, l4 = lane >> 4;
    int m0 = blockIdx.x * 128, n0 = blockIdx.y * 128;

    f32x4 zz = {0.f, 0.f, 0.f, 0.f};
    f32x4 acc[4][4];
#pragma unroll
    for (int m = 0; m < 4; m++)
#pragma unroll
        for (int n = 0; n < 4; n++) acc[m][n] = zz;

    auto STAGE = [&](int buf, int k0) {
#pragma unroll
        for (int i = 0; i < 4; i++) {
            int c = i * 256 + t;                 // 16B-chunk index 0..1023
            int row = c >> 3;
            int ch = (c & 7) ^ (row & 7);        // pre-swizzled source chunk
            async16(&As[buf][c * 8], A  + (size_t)(m0 + row) * K + k0 + ch * 8);
            async16(&Bs[buf][c * 8], Bw + (size_t)(n0 + row) * K + k0 + ch * 8);
        }
    };

    STAGE(0, 0);
    __syncthreads();            // tile 0 ready

    int KT = K >> 6, cur = 0;
    for (int kt = 0; kt < KT; kt++) {
        if (kt + 1 < KT) STAGE(cur ^ 1, (kt + 1) << 6);   // prefetch overlaps compute

        bf16x8 af[4][2], bfr[4][2];
#pragma unroll
        for (int ks = 0; ks < 2; ks++) {
#pragma unroll
            for (int m = 0; m < 4; m++) {
                int row = wm * 64 + m * 16 + l15;
                int ch = (l4 + 4 * ks) ^ (row & 7);
                af[m][ks] = *(const bf16x8*)&As[cur][row * 64 + ch * 8];
            }
#pragma unroll
            for (int n = 0; n < 4; n++) {
                int row = wn * 64 + n * 16 + l15;
                int ch = (l4 + 4 * ks) ^ (row & 7);
                bfr[n][ks] = *(const bf16x8*)&Bs[cur][row * 64 + ch * 8];
            }
        }
#pragma unroll
        for (int m = 0; m < 4; m++)
#pragma unroll
            for (int n = 0; n < 4; n++) {
                acc[m][n] = __builtin_amdgcn_mfma_f32_16x16x32_bf16(af[m][0], bfr[n][0], acc[m][n], 0, 0, 0);
                acc[m][n] = __builtin_amdgcn_mfma_f32_16x16x32_bf16(af[m][1], bfr[n][1], acc[m][n], 0, 0, 0);
            }

        __syncthreads();        // next tile staged + cur reads done
        cur ^= 1;
    }

#pragma unroll
    for (int m = 0; m < 4; m++)
#pragma unroll
        for (int n = 0; n < 4; n++) {
            int colb = n0 + wn * 64 + n * 16 + l15;
            int rowb = m0 + wm * 64 + m * 16 + l4 * 4;
            if (mode == 1) {
#pragma unroll
                for (int r = 0; r < 4; r++)
                    ((float*)Cout)[(size_t)(rowb + r) * N + colb] = acc[m][n][r];
            } else {
                if (colb < 2048) {
#pragma unroll
                    for (int r = 0; r < 4; r++) {
                        float c = acc[m][n][r];
                        c = (c > 0.f) ? (c + 1.f) : __expf(c);
                        ((u16*)Cout)[(size_t)(rowb + r) * N + colb] = f2bf(c);
                    }
                } else {
                    int vcol = colb - 2048;
                    int bb = rowb >> 11;
                    ushort4 o;
                    o.x = f2bf(acc[m][n][0]); o.y = f2bf(acc[m][n][1]);
                    o.z = f2bf(acc[m][n][2]); o.w = f2bf(acc[m][n][3]);
                    *(ushort4*)&Vtb[((size_t)((bb * 16 + (vcol >> 6)) * 64 + (vcol & 63))) * 2048 + (rowb & 2047)] = o;
                }
            }
        }
}

// ---------------------------------------------------------------------------
// Attention: swapped-QK 32x32x16 MFMA, global_load_lds dbuf staging,
// linear+XOR-swizzled LDS tiles, XCD-pinned bh, heavy-first iT, T5 setprio.
// ---------------------------------------------------------------------------
__global__ __launch_bounds__(128, 2)
void attn_mfma(const u16* __restrict__ QKV, const u16* __restrict__ Vtb,
               const float* __restrict__ CCg, const float* __restrict__ CJWg,
               u16* __restrict__ AOb) {
    __shared__ u16 Ks[2][4096];     // [64 j][64 k], swizzled
    __shared__ u16 Vs[2][4096];     // [64 dh][64 j], swizzled
    __shared__ float cjws[2048];

    // XCD-aware decode: same bh -> same XCD (id%8), heavy iT dispatched first
    int id = (int)blockIdx.x;
    int bh = ((id & 7) << 2) | ((id >> 3) & 3);
    int iT = 31 - (id >> 5);
    int b = bh >> 4, h = bh & 15;
    int i0 = iT * 64;
    int t = threadIdx.x, w = t >> 6, lane = t & 63;
    int l31 = lane & 31, hi = lane >> 5;
    int w32 = w * 32;

    // stage CJW for this (b,h) once (drained by prologue syncthreads)
#pragma unroll
    for (int rnd = 0; rnd < 4; rnd++) {
        int c = rnd * 128 + t;
        async16(&cjws[c * 4], CJWg + (size_t)bh * L_ + c * 4);
    }

    // Q fragments + ci straight from global (once per block)
    const u16* qbase = QKV + (size_t)(b * L_ + i0 + w32 + l31) * QKV_N + h * DH;
    bf16x8 qb[4];
#pragma unroll
    for (int ks = 0; ks < 4; ks++)
        qb[ks] = *(const bf16x8*)(qbase + ks * 16 + hi * 8);
    float ci = CCg[(size_t)bh * L_ + i0 + w32 + l31];

    const u16* kbg0 = QKV + 1024 + (size_t)(b * L_) * QKV_N + h * DH;
    const u16* vbg0 = Vtb + (size_t)(bh * 64) * 2048;

    auto STAGE = [&](int buf, int jt) {
        int j0s = jt * 64;
#pragma unroll
        for (int rnd = 0; rnd < 4; rnd++) {
            int c = rnd * 128 + t;               // chunk 0..511
            int row = c >> 3;                    // j row
            int ch = (c & 7) ^ (row & 7);        // pre-swizzled k-chunk
            async16(&Ks[buf][c * 8], kbg0 + (size_t)(j0s + row) * QKV_N + ch * 8);
        }
#pragma unroll
        for (int rnd = 0; rnd < 4; rnd++) {
            int c = rnd * 128 + t;
            int dh = c >> 3;
            int jc = (c & 7) ^ (dh & 7);         // pre-swizzled j-chunk
            async16(&Vs[buf][c * 8], vbg0 + (size_t)dh * 2048 + j0s + jc * 8);
        }
    };

    f32x16 z16;
#pragma unroll
    for (int r = 0; r < 16; r++) z16[r] = 0.f;
    f32x16 acc[2];
    acc[0] = z16; acc[1] = z16;
    float dloc = 0.f;

    STAGE(0, 0);
    __syncthreads();   // drains vmcnt: tile 0 + cjws ready

    int cur = 0;
    int lim = w32 + l31;       // local row within the 64-row i-tile
    for (int jt = 0; jt <= iT; ++jt) {
        int j0 = jt * 64;
        bool diag = (jt == iT);
        if (jt < iT) STAGE(cur ^ 1, jt + 1);   // prefetch overlaps compute

        // ---- QK^T swapped: st[n] = S^T frag, S[j][i], i = l31 ----
        f32x16 st[2];
        st[0] = z16; st[1] = z16;
        int swz = (l31 & 7);
        __builtin_amdgcn_s_setprio(1);
#pragma unroll
        for (int ks = 0; ks < 4; ks++) {
            int ch = (ks * 2 + hi) ^ swz;        // same low-3 bits for l31 and l31+32
            bf16x8 k0 = *(const bf16x8*)&Ks[cur][l31 * 64 + ch * 8];
            bf16x8 k1 = *(const bf16x8*)&Ks[cur][(32 + l31) * 64 + ch * 8];
            st[0] = __builtin_amdgcn_mfma_f32_32x32x16_bf16(k0, qb[ks], st[0], 0, 0, 0);
            st[1] = __builtin_amdgcn_mfma_f32_32x32x16_bf16(k1, qb[ks], st[1], 0, 0, 0);
        }
        __builtin_amdgcn_s_setprio(0);

        // ---- decay/gate/mask in-register, pack to bf16 quads ----
        unsigned pk[2][4][2];
#pragma unroll
        for (int n = 0; n < 2; n++) {
#pragma unroll
            for (int rq = 0; rq < 4; rq++) {
                float4 cj4 = *(const float4*)&cjws[j0 + n * 32 + rq * 8 + hi * 4];
                float e0 = st[n][rq * 4 + 0] * fexp2(ci - cj4.x);
                float e1 = st[n][rq * 4 + 1] * fexp2(ci - cj4.y);
                float e2 = st[n][rq * 4 + 2] * fexp2(ci - cj4.z);
                float e3 = st[n][rq * 4 + 3] * fexp2(ci - cj4.w);
                if (diag) {
                    int jb = n * 32 + rq * 8 + hi * 4;
                    e0 = (jb + 0 <= lim) ? e0 : 0.f;
                    e1 = (jb + 1 <= lim) ? e1 : 0.f;
                    e2 = (jb + 2 <= lim) ? e2 : 0.f;
                    e3 = (jb + 3 <= lim) ? e3 : 0.f;
                }
                dloc += (e0 + e1) + (e2 + e3);
                asm("v_cvt_pk_bf16_f32 %0, %1, %2" : "=v"(pk[n][rq][0]) : "v"(e0), "v"(e1));
                asm("v_cvt_pk_bf16_f32 %0, %1, %2" : "=v"(pk[n][rq][1]) : "v"(e2), "v"(e3));
            }
        }

        // ---- assemble PV A-frags via permlane32_swap, multiply against V ----
        __builtin_amdgcn_s_setprio(1);
#pragma unroll
        for (int wi = 0; wi < 4; wi++) {
            int n = wi >> 1, qA = 2 * (wi & 1), qB = qA + 1;
            unsigned a0 = pk[n][qA][0], b0 = pk[n][qB][0];
            unsigned a1 = pk[n][qA][1], b1 = pk[n][qB][1];
            asm volatile("v_permlane32_swap_b32 %0, %1" : "+v"(a0), "+v"(b0));
            asm volatile("v_permlane32_swap_b32 %0, %1" : "+v"(a1), "+v"(b1));
            union { unsigned u[4]; bf16x8 v; } aw;
            aw.u[0] = a0; aw.u[1] = a1; aw.u[2] = b0; aw.u[3] = b1;
#pragma unroll
            for (int m = 0; m < 2; m++) {
                int dh = m * 32 + l31;
                int jc = (wi * 2 + hi) ^ (dh & 7);
                bf16x8 vb = *(const bf16x8*)&Vs[cur][dh * 64 + jc * 8];
                acc[m] = __builtin_amdgcn_mfma_f32_32x32x16_bf16(aw.v, vb, acc[m], 0, 0, 0);
            }
        }
        __builtin_amdgcn_s_setprio(0);

        __syncthreads();   // drains vmcnt: next tile staged, cur reads done
        cur ^= 1;
    }

    // denominator: other hi-half holds the rest of row i = l31
    float dtot = dloc + __shfl_xor(dloc, 32, 64);
    float dr[16];
#pragma unroll
    for (int r = 0; r < 16; r++) {
        int il = (r & 3) + 8 * (r >> 2) + 4 * hi;
        dr[r] = __shfl(dtot, il, 64);
    }
#pragma unroll
    for (int m = 0; m < 2; m++)
#pragma unroll
        for (int r = 0; r < 16; r++) {
            int il = (r & 3) + 8 * (r >> 2) + 4 * hi;
            float o = acc[m][r] / (dr[r] + 1e-6f);
            int ig = i0 + w32 + il;
            AOb[(size_t)(b * L_ + ig) * D_ + h * DH + m * 32 + l31] = f2bf(o);
        }
}

// ---------------------------------------------------------------------------
extern "C" void kernel_launch(void* const* d_in, const int* in_sizes, int n_in,
                              void* d_out, int out_size, void* d_ws, size_t ws_size,
                              hipStream_t stream) {
    const float* x  = (const float*)d_in[0];
    const float* Wq = (const float*)d_in[1];
    const float* Wk = (const float*)d_in[2];
    const float* Wv = (const float*)d_in[3];
    const float* Wo = (const float*)d_in[4];
    const float* Ww = (const float*)d_in[5];
    const float* bw = (const float*)d_in[6];
    const float* We = (const float*)d_in[7];
    const float* be = (const float*)d_in[8];
    float* out = (float*)d_out;

    char* wsb = (char*)d_ws;
    u16* xb   = (u16*)(wsb);                        // 8MB
    u16* Wcat = (u16*)(wsb + ((size_t)8  << 20));   // 8MB  [Wq;Wk;Wv;Wo] bf16
    u16* QKV  = (u16*)(wsb + ((size_t)16 << 20));   // 24MB [4096][3072] (V cols unused)
    u16* Vtb  = (u16*)(wsb + ((size_t)40 << 20));   // 8MB  [B*H*64][2048]
    u16* AOb  = (u16*)(wsb + ((size_t)48 << 20));   // 8MB  [4096][1024]
    float* GLOG = (float*)(wsb + ((size_t)56 << 20));
    float* LWG  = GLOG + 65536;
    float* CC   = LWG  + 65536;
    float* CJW  = CC   + 65536;

    gates_castx<<<ML / 16, 256, 0, stream>>>(x, Ww, bw, We, be, xb, GLOG, LWG);
    cast_w4<<<4096, 256, 0, stream>>>(Wq, Wk, Wv, Wo, Wcat);
    scan_kernel<<<B_ * H_, 64, 0, stream>>>(GLOG, LWG, CC, CJW);

    // fused Q,K,V projection: phi on Q,K; V written transposed into Vtb
    gemm_mfma_bt<<<dim3(ML / 128, QKV_N / 128), 256, 0, stream>>>(
        xb, Wcat, QKV, Vtb, ML, QKV_N, D_, 2);

    attn_mfma<<<dim3(32 * 32), 128, 0, stream>>>(QKV, Vtb, CC, CJW, AOb);

    gemm_mfma_bt<<<dim3(ML / 128, D_ / 128), 256, 0, stream>>>(
        AOb, Wcat + (size_t)3072 * 1024, out, Vtb, ML, D_, D_, 1);
}